// Round 18
// baseline (42.480 us; speedup 1.0000x reference)
//
#include <hip/hip_runtime.h>
#include <hip/hip_bf16.h>

typedef __attribute__((ext_vector_type(8)))  short  short8_t;
typedef __attribute__((ext_vector_type(4)))  float  float4_t;
typedef __attribute__((ext_vector_type(16))) float  f32x16_t;
typedef __attribute__((ext_vector_type(4)))  int    int4_t;
typedef __attribute__((ext_vector_type(2)))  unsigned int uint2_t;

// f32 -> bf16 RNE (bit-twiddle; prepass/fallback)
__device__ __forceinline__ unsigned short f2bf(float f) {
    unsigned int u = __builtin_bit_cast(unsigned int, f);
    u += 0x7FFFu + ((u >> 16) & 1u);
    return (unsigned short)(u >> 16);
}
__device__ __forceinline__ unsigned int cvtpk(float a, float b) {
    return (unsigned int)f2bf(a) | ((unsigned int)f2bf(b) << 16);
}
// HW packed convert (no builtin on gfx950)
__device__ __forceinline__ unsigned int cvtpk_hw(float a, float b) {
    unsigned int r;
    asm("v_cvt_pk_bf16_f32 %0, %1, %2" : "=v"(r) : "v"(a), "v"(b));
    return r;
}
// lane i (i<32) <-> lane i+32 (fallback path only)
__device__ __forceinline__ void plane32_swap(unsigned int& a, unsigned int& b) {
    asm("v_permlane32_swap_b32 %0, %1" : "+v"(a), "+v"(b));
}

// ---- prepass (verified R13) ----
// W2t granule layout (32x32x16 A-frags): granule g = (ks*8+et)*64+lane,
//   value = W2[et*32+(lane&31)][ks*16+(lane>>5)*8 .. +8)  (bf16 x8, 16B)
// W1b: 1024 x 8 bf16 row-major
__global__ void prep_kernel(const float* __restrict__ W2, const float* __restrict__ W1,
                            unsigned short* __restrict__ W2t, unsigned short* __restrict__ W1b) {
    const int bid = blockIdx.x, tid = threadIdx.x;
    if (bid < 128) {
        const int g   = bid * 256 + tid;
        const int l   = g & 63;
        const int pos = g >> 6;                   // ks*8+et
        const int ks  = pos >> 3;
        const int et  = pos & 7;
        const int e   = et * 32 + (l & 31);
        const int f0  = ks * 16 + (l >> 5) * 8;
        const float* src = W2 + (size_t)e * 1024 + f0;
        const float4_t v0 = *reinterpret_cast<const float4_t*>(src);
        const float4_t v1 = *reinterpret_cast<const float4_t*>(src + 4);
        int4_t p;
        p[0] = (int)cvtpk(v0[0], v0[1]);
        p[1] = (int)cvtpk(v0[2], v0[3]);
        p[2] = (int)cvtpk(v1[0], v1[1]);
        p[3] = (int)cvtpk(v1[2], v1[3]);
        *reinterpret_cast<int4_t*>(W2t + (size_t)g * 8) = p;
    } else {
        const int base = tid * 32;
        #pragma unroll
        for (int it = 0; it < 8; ++it) {
            const float4_t v = *reinterpret_cast<const float4_t*>(W1 + base + it * 4);
            uint2_t p;
            p[0] = cvtpk(v[0], v[1]);
            p[1] = cvtpk(v[2], v[3]);
            *reinterpret_cast<uint2_t*>(W1b + base + it * 4) = p;
        }
    }
}

// ---- fused; block = 32 rows x 128 cols (wave owns ONE 32-col e-tile) ----
// h computed once per block per chunk into LDS (B-frag granule layout, no permlane).
// Per main step: {1 ds_read_b128 + 1 L2 load + 1 MFMA}. 2048 blocks, LDS 16 KB,
// acc 16 VGPR -> 8 blocks/CU (32 waves/CU, 100% occupancy target).
template <bool WSOK>
__global__ __launch_bounds__(256, 8)
void ffq_kernel(const float* __restrict__ x,
                const float* __restrict__ theta,
                const float* __restrict__ W1f,
                const unsigned short* __restrict__ W1b,
                const float* __restrict__ W2f,
                const unsigned short* __restrict__ W2t,
                float* __restrict__ out)
{
    // h chunk buffer: granule gidx<32 (= local ks*2 + hi), m<32, 8 bf16 (16B)
    __shared__ __align__(16) unsigned short hL[32 * 32 * 8];   // 16 KB

    const int tid  = threadIdx.x;
    const int lane = tid & 63;
    const int w    = tid >> 6;
    const int bid  = blockIdx.x;
    const int ct      = bid & 1;                  // 128-col half
    const int rowbase = (bid >> 1) * 32;          // 1024 row-stripes of 32
    const int m  = lane & 31;
    const int hi = lane >> 5;

    // ---- q B-frag: lane<32 holds q[rowbase+m][0..7] bf16; hi lanes ZERO (K pad) ----
    short8_t qf = {0,0,0,0,0,0,0,0};
    if (lane < 32) {
        const float* xp = x + (size_t)(rowbase + m) * 256;
        const float4_t x0 = *reinterpret_cast<const float4_t*>(xp);
        const float4_t x1 = *reinterpret_cast<const float4_t*>(xp + 4);
        float qv[8];
        #pragma unroll
        for (int j = 0; j < 4; ++j) {
            qv[j]     = __cosf(x0[j]) * __cosf(theta[j]);
            qv[4 + j] = __cosf(x1[j]) * __cosf(theta[4 + j]);
        }
        int4_t pq;
        pq[0] = (int)cvtpk(qv[0], qv[1]);
        pq[1] = (int)cvtpk(qv[2], qv[3]);
        pq[2] = (int)cvtpk(qv[4], qv[5]);
        pq[3] = (int)cvtpk(qv[6], qv[7]);
        qf = __builtin_bit_cast(short8_t, pq);
    }

    f32x16_t acc0 = {0};
    #pragma unroll
    for (int i = 0; i < 16; ++i) acc0[i] = 0.f;
    f32x16_t zz = acc0;   // zero C-operand for h-MFMA

    if constexpr (WSOK) {
        #pragma unroll 1
        for (int c = 0; c < 4; ++c) {
            __syncthreads();   // previous chunk's reads of hL complete

            // ---- h-phase: wave w computes f-tiles ftl = 2w, 2w+1 of this chunk ----
            #pragma unroll
            for (int i = 0; i < 2; ++i) {
                const int ftl = w * 2 + i;                 // local f-tile 0..7
                const int ftg = c * 8 + ftl;               // global f-tile 0..31
                // A-frag: A[f=ftg*32+m][k=hi*8+j]; hi=1 reads next row (finite,
                // annihilated by qf's zero hi-k) — 16B per lane from L2.
                const short8_t af = *reinterpret_cast<const short8_t*>(
                    (const char*)W1b + (size_t)(ftg * 32 + m) * 16 + hi * 16);
                const f32x16_t d = __builtin_amdgcn_mfma_f32_32x32x16_bf16(af, qf, zz, 0, 0, 0);
                // D[f',m]: f' = (r&3) + 8*(r>>2) + 4*hi. Block b (=f'>>3): lane hi
                // holds j=4*hi..4*hi+3 -> ds_write_b64 at granule(ftl*4+b, m)+hi*8B.
                #pragma unroll
                for (int b = 0; b < 4; ++b) {
                    uint2_t pk;
                    pk[0] = cvtpk_hw(fmaxf(d[4*b+0], 0.f), fmaxf(d[4*b+1], 0.f));
                    pk[1] = cvtpk_hw(fmaxf(d[4*b+2], 0.f), fmaxf(d[4*b+3], 0.f));
                    *reinterpret_cast<uint2_t*>(
                        &hL[((ftl * 4 + b) * 32 + m) * 8 + hi * 4]) = pk;
                }
            }

            __syncthreads();   // h chunk published

            // ---- main loop: pure {ds_read, 1 L2 load, 1 MFMA} x 16 ----
            #pragma unroll 4
            for (int ksl = 0; ksl < 16; ++ksl) {
                const short8_t bf = *reinterpret_cast<const short8_t*>(
                    &hL[((ksl * 2 + hi) * 32 + m) * 8]);
                const int ks = c * 16 + ksl;
                const short8_t a0 = *reinterpret_cast<const short8_t*>(
                    W2t + (size_t)(ks * 8 + ct * 4 + w) * 512 + lane * 8);
                acc0 = __builtin_amdgcn_mfma_f32_32x32x16_bf16(a0, bf, acc0, 0, 0, 0);
            }
        }
    } else {
        // fallback (no workspace): register-direct per-step htr (R16-verified form)
        short8_t bf0, bf1;
        auto htr = [&](short8_t af) {
            const f32x16_t d = __builtin_amdgcn_mfma_f32_32x32x16_bf16(af, qf, zz, 0, 0, 0);
            unsigned int U00 = cvtpk_hw(fmaxf(d[0],  0.f), fmaxf(d[1],  0.f));
            unsigned int U01 = cvtpk_hw(fmaxf(d[2],  0.f), fmaxf(d[3],  0.f));
            unsigned int U10 = cvtpk_hw(fmaxf(d[4],  0.f), fmaxf(d[5],  0.f));
            unsigned int U11 = cvtpk_hw(fmaxf(d[6],  0.f), fmaxf(d[7],  0.f));
            unsigned int U20 = cvtpk_hw(fmaxf(d[8],  0.f), fmaxf(d[9],  0.f));
            unsigned int U21 = cvtpk_hw(fmaxf(d[10], 0.f), fmaxf(d[11], 0.f));
            unsigned int U30 = cvtpk_hw(fmaxf(d[12], 0.f), fmaxf(d[13], 0.f));
            unsigned int U31 = cvtpk_hw(fmaxf(d[14], 0.f), fmaxf(d[15], 0.f));
            plane32_swap(U00, U10);
            plane32_swap(U01, U11);
            plane32_swap(U20, U30);
            plane32_swap(U21, U31);
            int4_t p0; p0[0]=(int)U00; p0[1]=(int)U01; p0[2]=(int)U10; p0[3]=(int)U11;
            int4_t p1; p1[0]=(int)U20; p1[1]=(int)U21; p1[2]=(int)U30; p1[3]=(int)U31;
            bf0 = __builtin_bit_cast(short8_t, p0);
            bf1 = __builtin_bit_cast(short8_t, p1);
        };
        for (int s = 0; s < 32; ++s) {
            const float* ws = W1f + (size_t)(s * 32 + m) * 8;
            const float4_t a0 = *reinterpret_cast<const float4_t*>(ws);
            const float4_t a1 = *reinterpret_cast<const float4_t*>(ws + 4);
            int4_t pa;
            pa[0] = (int)cvtpk(a0[0], a0[1]);
            pa[1] = (int)cvtpk(a0[2], a0[3]);
            pa[2] = (int)cvtpk(a1[0], a1[1]);
            pa[3] = (int)cvtpk(a1[2], a1[3]);
            htr(__builtin_bit_cast(short8_t, pa));
            const int e = ct * 128 + w * 32 + m;
            #pragma unroll
            for (int kw = 0; kw < 2; ++kw) {
                const float* p = W2f + (size_t)e * 1024 + (s * 32 + kw * 16) + hi * 8;
                const float4_t v0 = *reinterpret_cast<const float4_t*>(p);
                const float4_t v1 = *reinterpret_cast<const float4_t*>(p + 4);
                int4_t pb;
                pb[0] = (int)cvtpk(v0[0], v0[1]);
                pb[1] = (int)cvtpk(v0[2], v0[3]);
                pb[2] = (int)cvtpk(v1[0], v1[1]);
                pb[3] = (int)cvtpk(v1[2], v1[3]);
                const short8_t fb = __builtin_bit_cast(short8_t, pb);
                acc0 = __builtin_amdgcn_mfma_f32_32x32x16_bf16(
                    fb, (kw == 0) ? bf0 : bf1, acc0, 0, 0, 0);
            }
        }
    }

    // ---- epilogue: out^T store (verified). D[e][m]: col m, e=(r&3)+8(r>>2)+4hi ----
    {
        float* orow = out + (size_t)(rowbase + m) * 256 + ct * 128 + w * 32 + hi * 4;
        #pragma unroll
        for (int rq = 0; rq < 4; ++rq) {
            float4_t v;
            v[0] = acc0[4*rq+0]; v[1] = acc0[4*rq+1];
            v[2] = acc0[4*rq+2]; v[3] = acc0[4*rq+3];
            *reinterpret_cast<float4_t*>(orow + rq * 8) = v;
        }
    }
}

extern "C" void kernel_launch(void* const* d_in, const int* in_sizes, int n_in,
                              void* d_out, int out_size, void* d_ws, size_t ws_size,
                              hipStream_t stream) {
    const float* x     = (const float*)d_in[0];   // [8,4096,256]
    const float* theta = (const float*)d_in[1];   // [8]
    const float* W1    = (const float*)d_in[2];   // [1024,8]
    const float* W2    = (const float*)d_in[3];   // [256,1024]
    float* out = (float*)d_out;                   // [8,4096,256] f32

    // need W2t (512KB) + W1b (16KB) + 16B slack for the hi=1 tail read
    const size_t need = (size_t)(256 * 1024 + 1024 * 8) * sizeof(unsigned short) + 16;
    const bool wsok = (ws_size >= need);

    if (wsok) {
        unsigned short* W2t = (unsigned short*)d_ws;   // 512KB, 32x32x16-A granule layout
        unsigned short* W1b = W2t + 256 * 1024;        // 16KB bf16
        prep_kernel<<<129, 256, 0, stream>>>(W2, W1, W2t, W1b);
        ffq_kernel<true><<<2048, 256, 0, stream>>>(x, theta, nullptr, W1b, nullptr, W2t, out);
    } else {
        ffq_kernel<false><<<2048, 256, 0, stream>>>(x, theta, W1, nullptr, W2, nullptr, out);
    }
}